// Round 9
// baseline (346.034 us; speedup 1.0000x reference)
//
#include <hip/hip_runtime.h>

#define NUSERS 100000
#define NITEMS 50000
#define DIM 64
#define NNZ 1600000
#define ALPHA 0.1f
#define TROWS (NUSERS + NITEMS)   // 150000 combined rows
#define LSTRIDE (TROWS * DIM)
#define NEDGES (2 * NNZ)          // 3.2M combined edges

#define BROWS 128                           // rows per bucket
#define NBUCK ((TROWS + BROWS - 1) / BROWS) // 1172
#define NSEG (NBUCK * 8)                    // wave segments (8 row-groups/bucket)

#define CH_H 4096                               // edges per hist block
#define NCHUNK_H ((NEDGES + CH_H - 1) / CH_H)   // 782
#define CH_S 8192                               // edges per scatter block
#define NCHUNK_S ((NEDGES + CH_S - 1) / CH_S)   // 391

__device__ __forceinline__ unsigned short f2bf(float f) {
    unsigned u = __float_as_uint(f);
    unsigned r = (u + 0x7FFFu + ((u >> 16) & 1u)) >> 16;   // RNE
    return (unsigned short)r;
}

__device__ __forceinline__ float bf2f(unsigned short b) {
    return __uint_as_float(((unsigned)b) << 16);
}

// ---------------- layer-0 copy + bf16 table ----------------
template <int MAKE_BF16>
__global__ __launch_bounds__(256) void init_copy_kernel(const float4* __restrict__ ue,
                                                        const float4* __restrict__ ie,
                                                        float4* __restrict__ out,
                                                        ushort4* __restrict__ xb0) {
    const int nU4 = NUSERS * DIM / 4;
    const int nT4 = TROWS * DIM / 4;
    int i = blockIdx.x * 256 + threadIdx.x;
    if (i >= nT4) return;
    float4 v = (i < nU4) ? ue[i] : ie[i - nU4];
    out[i] = v;
    if (MAKE_BF16) {
        ushort4 b;
        b.x = f2bf(v.x); b.y = f2bf(v.y); b.z = f2bf(v.z); b.w = f2bf(v.w);
        xb0[i] = b;
    }
}

// ---------------- bucket histogram (block-privatized, int LDS atomics) ----------------
__global__ __launch_bounds__(256) void bucket_hist_kernel(const int* __restrict__ ui_rows,
                                                          const int* __restrict__ iu_rows,
                                                          int* __restrict__ gcounts) {
    __shared__ int h[NBUCK];
    for (int t = threadIdx.x; t < NBUCK; t += 256) h[t] = 0;
    __syncthreads();
    int base = blockIdx.x * CH_H;
    for (int j = threadIdx.x; j < CH_H; j += 256) {
        int i = base + j;
        if (i >= NEDGES) break;
        int crow = (i < NNZ) ? ui_rows[i] : (NUSERS + iu_rows[i - NNZ]);
        atomicAdd(&h[crow >> 7], 1);
    }
    __syncthreads();
    for (int t = threadIdx.x; t < NBUCK; t += 256) {
        int c = h[t];
        if (c) atomicAdd(&gcounts[t], c);
    }
}

// ---------------- exclusive scan of bucket counts (one wave) ----------------
__global__ void scan_buckets_kernel(const int* __restrict__ gcounts,
                                    int* __restrict__ gbase,
                                    int* __restrict__ gcursor) {
    int lane = threadIdx.x;   // blockDim = 64, single wave
    int carry = 0;
    for (int b0 = 0; b0 < NBUCK; b0 += 64) {
        int idx = b0 + lane;
        int c = (idx < NBUCK) ? gcounts[idx] : 0;
        int x = c;
        for (int off = 1; off < 64; off <<= 1) {
            int u = __shfl_up(x, off, 64);
            if (lane >= off) x += u;
        }
        int excl = carry + x - c;
        if (idx < NBUCK) { gbase[idx] = excl; gcursor[idx] = excl; }
        carry += __shfl(x, 63, 64);
    }
}

// ---------------- binned scatter: contiguous per-(block,bucket) runs ----------------
// payload word0 = src | (row_local << 18)   (src < 2^18, row_local < 128)
__global__ __launch_bounds__(512) void bin_scatter_kernel(
    const int* __restrict__ ui_rows, const int* __restrict__ ui_cols,
    const float* __restrict__ ui_vals,
    const int* __restrict__ iu_rows, const int* __restrict__ iu_cols,
    const float* __restrict__ iu_vals,
    int* __restrict__ gcursor, int2* __restrict__ binned)
{
    __shared__ int h[NBUCK];
    __shared__ int bbase[NBUCK];
    for (int t = threadIdx.x; t < NBUCK; t += 512) h[t] = 0;
    __syncthreads();
    int base = blockIdx.x * CH_S;
    for (int j = threadIdx.x; j < CH_S; j += 512) {
        int i = base + j;
        if (i >= NEDGES) break;
        int crow = (i < NNZ) ? ui_rows[i] : (NUSERS + iu_rows[i - NNZ]);
        atomicAdd(&h[crow >> 7], 1);
    }
    __syncthreads();
    for (int t = threadIdx.x; t < NBUCK; t += 512) {
        int c = h[t];
        bbase[t] = c ? atomicAdd(&gcursor[t], c) : 0;
        h[t] = 0;
    }
    __syncthreads();
    for (int j = threadIdx.x; j < CH_S; j += 512) {
        int i = base + j;
        if (i >= NEDGES) break;
        int crow, src; float val;
        if (i < NNZ) {
            crow = ui_rows[i]; src = NUSERS + ui_cols[i]; val = ui_vals[i];
        } else {
            int k = i - NNZ;
            crow = NUSERS + iu_rows[k]; src = iu_cols[k]; val = iu_vals[k];
        }
        int b = crow >> 7;
        int off = atomicAdd(&h[b], 1);
        binned[bbase[b] + off] = make_int2(src | ((crow & 127) << 18), __float_as_int(val));
    }
}

// ---------------- segment sort: key = (row_group, src_tile) ----------------
// Counting sort (128 keys) per bucket: groups the bucket's edges into 8 wave
// segments (16 rows each), src-tile-ordered (tile = src>>14, 2MB windows)
// inside each segment. Emits per-segment [start,end) and re-packs payload as
// src | (row16 << 18).
__global__ __launch_bounds__(512) void csr_seg_sort_kernel(
    const int* __restrict__ gbase, const int* __restrict__ gcounts,
    const int2* __restrict__ binned, int2* __restrict__ binned2,
    int2* __restrict__ segptr)
{
    __shared__ int h[128];
    __shared__ int off[128];
    __shared__ int cur[128];
    int b = blockIdx.x;
    int s = gbase[b];
    int n = gcounts[b];
    int t = threadIdx.x;
    if (t < 128) h[t] = 0;
    __syncthreads();
    for (int k = t; k < n; k += 512) {
        unsigned w = (unsigned)binned[s + k].x;
        int rl = (int)((w >> 18) & 127u);
        int src = (int)(w & 0x3FFFFu);
        int key = ((rl >> 4) << 4) | (src >> 14);   // < 128 (tile <= 9)
        atomicAdd(&h[key], 1);
    }
    __syncthreads();
    if (t < 128) off[t] = h[t];
    __syncthreads();
    for (int d = 1; d < 128; d <<= 1) {
        int v = 0;
        if (t < 128 && t >= d) v = off[t - d];
        __syncthreads();
        if (t < 128) off[t] += v;     // inclusive scan
        __syncthreads();
    }
    if (t < 128) cur[t] = off[t] - h[t];   // exclusive
    __syncthreads();
    if (t < 8) {
        int start = s + ((t == 0) ? 0 : off[t * 16 - 1]);
        int end   = (t == 7) ? (s + n) : (s + off[(t + 1) * 16 - 1]);
        segptr[b * 8 + t] = make_int2(start, end);
    }
    for (int k = t; k < n; k += 512) {
        int2 m = binned[s + k];
        unsigned w = (unsigned)m.x;
        int rl = (int)((w >> 18) & 127u);
        int src = (int)(w & 0x3FFFFu);
        int key = ((rl >> 4) << 4) | (src >> 14);
        int pos = atomicAdd(&cur[key], 1);
        binned2[s + pos] = make_int2(src | ((rl & 15) << 18), m.y);
    }
}

// ---------------- segmented pull: block/bucket, wave/16-rows, LDS accum ----------------
// Wave wid owns rows [b*128 + wid*16, +16) with a private LDS accumulator
// y[16][64] (lane = dim). Edges arrive src-tile-ordered; all co-resident
// waves sweep src space together -> gather hits cluster in L2. No atomics,
// no barriers (wave-private LDS). 8 gathers in flight per wave.
template <int WRITE_BF16>
__global__ __launch_bounds__(512) void pull_seg_kernel(
    const int2* __restrict__ segptr,
    const int2* __restrict__ cc,
    const unsigned short* __restrict__ xb_prev,  // bf16 gather table (prev layer)
    const unsigned short* __restrict__ xb0,      // bf16 layer-0 table (alpha residual)
    float* __restrict__ outL,                    // f32 combined output layer
    unsigned short* __restrict__ xb_next)        // bf16 table for next layer
{
    __shared__ float y[8 * 16 * 64];   // 32 KB, wave-private 4KB slices
    int b = blockIdx.x;
    int wid = threadIdx.x >> 6;
    int lane = threadIdx.x & 63;
    float* yw = &y[wid * 1024];
#pragma unroll
    for (int j = 0; j < 16; ++j) yw[j * 64 + lane] = 0.f;

    int2 seg = segptr[b * 8 + wid];
    int e = seg.x, end = seg.y;

    for (; e + 8 <= end; e += 8) {
        int2 m0 = cc[e],     m1 = cc[e + 1], m2 = cc[e + 2], m3 = cc[e + 3];
        int2 m4 = cc[e + 4], m5 = cc[e + 5], m6 = cc[e + 6], m7 = cc[e + 7];
        unsigned short x0 = xb_prev[(size_t)(m0.x & 0x3FFFF) * DIM + lane];
        unsigned short x1 = xb_prev[(size_t)(m1.x & 0x3FFFF) * DIM + lane];
        unsigned short x2 = xb_prev[(size_t)(m2.x & 0x3FFFF) * DIM + lane];
        unsigned short x3 = xb_prev[(size_t)(m3.x & 0x3FFFF) * DIM + lane];
        unsigned short x4 = xb_prev[(size_t)(m4.x & 0x3FFFF) * DIM + lane];
        unsigned short x5 = xb_prev[(size_t)(m5.x & 0x3FFFF) * DIM + lane];
        unsigned short x6 = xb_prev[(size_t)(m6.x & 0x3FFFF) * DIM + lane];
        unsigned short x7 = xb_prev[(size_t)(m7.x & 0x3FFFF) * DIM + lane];
        // lane-private LDS RMW; in-order LDS pipe keeps same-row edges correct
        yw[(((unsigned)m0.x >> 18) & 15) * 64 + lane] += __int_as_float(m0.y) * bf2f(x0);
        yw[(((unsigned)m1.x >> 18) & 15) * 64 + lane] += __int_as_float(m1.y) * bf2f(x1);
        yw[(((unsigned)m2.x >> 18) & 15) * 64 + lane] += __int_as_float(m2.y) * bf2f(x2);
        yw[(((unsigned)m3.x >> 18) & 15) * 64 + lane] += __int_as_float(m3.y) * bf2f(x3);
        yw[(((unsigned)m4.x >> 18) & 15) * 64 + lane] += __int_as_float(m4.y) * bf2f(x4);
        yw[(((unsigned)m5.x >> 18) & 15) * 64 + lane] += __int_as_float(m5.y) * bf2f(x5);
        yw[(((unsigned)m6.x >> 18) & 15) * 64 + lane] += __int_as_float(m6.y) * bf2f(x6);
        yw[(((unsigned)m7.x >> 18) & 15) * 64 + lane] += __int_as_float(m7.y) * bf2f(x7);
    }
    for (; e < end; ++e) {
        int2 m = cc[e];
        unsigned short x = xb_prev[(size_t)(m.x & 0x3FFFF) * DIM + lane];
        yw[(((unsigned)m.x >> 18) & 15) * 64 + lane] += __int_as_float(m.y) * bf2f(x);
    }

    // epilogue: + alpha*e0 (bf16 table), NT store f32, optional bf16 table
    int row0 = b * BROWS + wid * 16;
#pragma unroll
    for (int j = 0; j < 16; ++j) {
        int row = row0 + j;
        if (row >= TROWS) break;
        float acc = yw[j * 64 + lane];
        float e0 = bf2f(xb0[(size_t)row * DIM + lane]);
        float o = fmaf(ALPHA, e0, acc);
        __builtin_nontemporal_store(o, &outL[(size_t)row * DIM + lane]);
        if (WRITE_BF16) xb_next[(size_t)row * DIM + lane] = f2bf(o);
    }
}

// ---------------- fallback (round-1 atomic path) ----------------
__global__ __launch_bounds__(256) void init_out_kernel(const float4* __restrict__ ue,
                                                       const float4* __restrict__ ie,
                                                       float4* __restrict__ out) {
    const int nU4 = NUSERS * DIM / 4;
    const int nT4 = TROWS * DIM / 4;
    int i = blockIdx.x * 256 + threadIdx.x;
    if (i >= nT4) return;
    float4 v = (i < nU4) ? ue[i] : ie[i - nU4];
    out[i] = v;
    float4 a = make_float4(ALPHA * v.x, ALPHA * v.y, ALPHA * v.z, ALPHA * v.w);
    out[nT4 + i] = a;
    out[2 * nT4 + i] = a;
}

__global__ __launch_bounds__(256) void spmm_layer_kernel(
    const int* __restrict__ ui_rows, const int* __restrict__ ui_cols,
    const float* __restrict__ ui_vals,
    const int* __restrict__ iu_rows, const int* __restrict__ iu_cols,
    const float* __restrict__ iu_vals,
    const float* __restrict__ x_items, const float* __restrict__ x_users,
    float* __restrict__ y_users, float* __restrict__ y_items)
{
    unsigned tid = blockIdx.x * 256u + threadIdx.x;
    unsigned d = tid & 63u;
    unsigned e = tid >> 6;
    if (e < NNZ) {
        int r = ui_rows[e];
        int c = ui_cols[e];
        float v = ui_vals[e];
        atomicAdd(&y_users[r * DIM + d], v * x_items[c * DIM + d]);
    } else {
        e -= NNZ;
        if (e < NNZ) {
            int r = iu_rows[e];
            int c = iu_cols[e];
            float v = iu_vals[e];
            atomicAdd(&y_items[r * DIM + d], v * x_users[c * DIM + d]);
        }
    }
}

extern "C" void kernel_launch(void* const* d_in, const int* in_sizes, int n_in,
                              void* d_out, int out_size, void* d_ws, size_t ws_size,
                              hipStream_t stream) {
    const float* ue      = (const float*)d_in[0];
    const float* ie      = (const float*)d_in[1];
    const float* ui_vals = (const float*)d_in[2];
    const float* iu_vals = (const float*)d_in[3];
    const int*   ui_rows = (const int*)d_in[4];
    const int*   ui_cols = (const int*)d_in[5];
    const int*   iu_rows = (const int*)d_in[6];
    const int*   iu_cols = (const int*)d_in[7];
    float* out = (float*)d_out;

    float* L1 = out + (size_t)LSTRIDE;
    float* L2 = out + (size_t)2 * LSTRIDE;

    // ws layout: gcounts[1280] gbase[1280] gcursor[1280] | segptr int2[NSEG]
    //            | binned int2[NEDGES] | binned2 int2[NEDGES]
    //            | xb0 ushort[TROWS*64] | xb1 ushort[TROWS*64]
    const size_t NB_PAD = 1280;
    const size_t cnt_bytes    = NB_PAD * 3 * 4;              // 15360
    const size_t seg_bytes    = (size_t)NSEG * 8;            // 75008
    const size_t hdr_bytes    = cnt_bytes + seg_bytes;       // 90368, 8B-aligned
    const size_t binned_bytes = (size_t)NEDGES * 8;          // 25.6 MB
    const size_t xb_bytes     = (size_t)TROWS * DIM * 2;     // 19.2 MB
    const size_t need_bf16 = hdr_bytes + 2 * binned_bytes + 2 * xb_bytes;  // ~90 MB

    if (ws_size < need_bf16) {
        // fallback: atomic scatter path (round-1, known-good)
        const int nT4 = TROWS * DIM / 4;
        init_out_kernel<<<(nT4 + 255) / 256, 256, 0, stream>>>(
            (const float4*)ue, (const float4*)ie, (float4*)out);
        float* u1 = L1; float* i1 = L1 + (size_t)NUSERS * DIM;
        float* u2 = L2; float* i2 = L2 + (size_t)NUSERS * DIM;
        const unsigned nblocks = (2u * NNZ * 64u) / 256u;
        spmm_layer_kernel<<<nblocks, 256, 0, stream>>>(
            ui_rows, ui_cols, ui_vals, iu_rows, iu_cols, iu_vals, ie, ue, u1, i1);
        spmm_layer_kernel<<<nblocks, 256, 0, stream>>>(
            ui_rows, ui_cols, ui_vals, iu_rows, iu_cols, iu_vals, i1, u1, u2, i2);
        return;
    }

    int* gcounts = (int*)d_ws;
    int* gbase   = gcounts + NB_PAD;
    int* gcursor = gbase + NB_PAD;
    int2* segptr  = (int2*)((char*)d_ws + cnt_bytes);
    int2* binned  = (int2*)((char*)d_ws + hdr_bytes);
    int2* binned2 = (int2*)((char*)binned + binned_bytes);
    unsigned short* xb0 = (unsigned short*)((char*)binned2 + binned_bytes);
    unsigned short* xb1 = xb0 + (size_t)TROWS * DIM;

    hipMemsetAsync(gcounts, 0, NB_PAD * sizeof(int), stream);

    const int nT4 = TROWS * DIM / 4;
    init_copy_kernel<1><<<(nT4 + 255) / 256, 256, 0, stream>>>(
        (const float4*)ue, (const float4*)ie, (float4*)out, (ushort4*)xb0);

    bucket_hist_kernel<<<NCHUNK_H, 256, 0, stream>>>(ui_rows, iu_rows, gcounts);
    scan_buckets_kernel<<<1, 64, 0, stream>>>(gcounts, gbase, gcursor);
    bin_scatter_kernel<<<NCHUNK_S, 512, 0, stream>>>(
        ui_rows, ui_cols, ui_vals, iu_rows, iu_cols, iu_vals, gcursor, binned);
    csr_seg_sort_kernel<<<NBUCK, 512, 0, stream>>>(
        gbase, gcounts, binned, binned2, segptr);

    pull_seg_kernel<1><<<NBUCK, 512, 0, stream>>>(
        segptr, binned2, xb0, xb0, L1, xb1);
    pull_seg_kernel<0><<<NBUCK, 512, 0, stream>>>(
        segptr, binned2, xb1, xb0, L2, nullptr);
}

// Round 10
// 318.100 us; speedup vs baseline: 1.0878x; 1.0878x over previous
//
#include <hip/hip_runtime.h>

#define NUSERS 100000
#define NITEMS 50000
#define DIM 64
#define NNZ 1600000
#define ALPHA 0.1f
#define TROWS (NUSERS + NITEMS)   // 150000 combined rows
#define LSTRIDE (TROWS * DIM)
#define NEDGES (2 * NNZ)          // 3.2M combined edges

#define BROWS 64                            // rows per bucket
#define NBUCK ((TROWS + BROWS - 1) / BROWS) // 2344
#define NSEG (NBUCK * 16)                   // (wave,group) segments: 4x4 per bucket

#define CH_H 4096                               // edges per hist block
#define NCHUNK_H ((NEDGES + CH_H - 1) / CH_H)   // 782
#define CH_S 8192                               // edges per scatter block
#define NCHUNK_S ((NEDGES + CH_S - 1) / CH_S)   // 391

__device__ __forceinline__ unsigned short f2bf(float f) {
    unsigned u = __float_as_uint(f);
    unsigned r = (u + 0x7FFFu + ((u >> 16) & 1u)) >> 16;   // RNE
    return (unsigned short)r;
}

__device__ __forceinline__ float bf2f(unsigned short b) {
    return __uint_as_float(((unsigned)b) << 16);
}

// ---------------- layer-0 copy + bf16 table ----------------
template <int MAKE_BF16>
__global__ __launch_bounds__(256) void init_copy_kernel(const float4* __restrict__ ue,
                                                        const float4* __restrict__ ie,
                                                        float4* __restrict__ out,
                                                        ushort4* __restrict__ xb0) {
    const int nU4 = NUSERS * DIM / 4;
    const int nT4 = TROWS * DIM / 4;
    int i = blockIdx.x * 256 + threadIdx.x;
    if (i >= nT4) return;
    float4 v = (i < nU4) ? ue[i] : ie[i - nU4];
    out[i] = v;
    if (MAKE_BF16) {
        ushort4 b;
        b.x = f2bf(v.x); b.y = f2bf(v.y); b.z = f2bf(v.z); b.w = f2bf(v.w);
        xb0[i] = b;
    }
}

// ---------------- bucket histogram (block-privatized, int LDS atomics) ----------------
__global__ __launch_bounds__(256) void bucket_hist_kernel(const int* __restrict__ ui_rows,
                                                          const int* __restrict__ iu_rows,
                                                          int* __restrict__ gcounts) {
    __shared__ int h[NBUCK];
    for (int t = threadIdx.x; t < NBUCK; t += 256) h[t] = 0;
    __syncthreads();
    int base = blockIdx.x * CH_H;
    for (int j = threadIdx.x; j < CH_H; j += 256) {
        int i = base + j;
        if (i >= NEDGES) break;
        int crow = (i < NNZ) ? ui_rows[i] : (NUSERS + iu_rows[i - NNZ]);
        atomicAdd(&h[crow >> 6], 1);
    }
    __syncthreads();
    for (int t = threadIdx.x; t < NBUCK; t += 256) {
        int c = h[t];
        if (c) atomicAdd(&gcounts[t], c);
    }
}

// ---------------- exclusive scan of bucket counts (one wave) ----------------
__global__ void scan_buckets_kernel(const int* __restrict__ gcounts,
                                    int* __restrict__ gbase,
                                    int* __restrict__ gcursor) {
    int lane = threadIdx.x;   // blockDim = 64, single wave
    int carry = 0;
    for (int b0 = 0; b0 < NBUCK; b0 += 64) {
        int idx = b0 + lane;
        int c = (idx < NBUCK) ? gcounts[idx] : 0;
        int x = c;
        for (int off = 1; off < 64; off <<= 1) {
            int u = __shfl_up(x, off, 64);
            if (lane >= off) x += u;
        }
        int excl = carry + x - c;
        if (idx < NBUCK) { gbase[idx] = excl; gcursor[idx] = excl; }
        carry += __shfl(x, 63, 64);
    }
}

// ---------------- binned scatter: contiguous per-(block,bucket) runs ----------------
// payload word0 = src | (row_local << 18)   (src < 2^18, row_local < 64)
__global__ __launch_bounds__(512) void bin_scatter_kernel(
    const int* __restrict__ ui_rows, const int* __restrict__ ui_cols,
    const float* __restrict__ ui_vals,
    const int* __restrict__ iu_rows, const int* __restrict__ iu_cols,
    const float* __restrict__ iu_vals,
    int* __restrict__ gcursor, int2* __restrict__ binned)
{
    __shared__ int h[NBUCK];
    __shared__ int bbase[NBUCK];
    for (int t = threadIdx.x; t < NBUCK; t += 512) h[t] = 0;
    __syncthreads();
    int base = blockIdx.x * CH_S;
    for (int j = threadIdx.x; j < CH_S; j += 512) {
        int i = base + j;
        if (i >= NEDGES) break;
        int crow = (i < NNZ) ? ui_rows[i] : (NUSERS + iu_rows[i - NNZ]);
        atomicAdd(&h[crow >> 6], 1);
    }
    __syncthreads();
    for (int t = threadIdx.x; t < NBUCK; t += 512) {
        int c = h[t];
        bbase[t] = c ? atomicAdd(&gcursor[t], c) : 0;
        h[t] = 0;
    }
    __syncthreads();
    for (int j = threadIdx.x; j < CH_S; j += 512) {
        int i = base + j;
        if (i >= NEDGES) break;
        int crow, src; float val;
        if (i < NNZ) {
            crow = ui_rows[i]; src = NUSERS + ui_cols[i]; val = ui_vals[i];
        } else {
            int k = i - NNZ;
            crow = NUSERS + iu_rows[k]; src = iu_cols[k]; val = iu_vals[k];
        }
        int b = crow >> 6;
        int off = atomicAdd(&h[b], 1);
        binned[bbase[b] + off] = make_int2(src | ((crow & 63) << 18), __float_as_int(val));
    }
}

// ---------------- segment sort: key = (4-row segment, src_tile) ----------------
// Counting sort (256 keys) per 64-row bucket: 16 segments x 16 tile slots.
// Segment seg owns rows [seg*4, seg*4+4); within a segment edges are
// src-tile-ordered (tile = src>>14, 2MB windows). Payload re-packed as
// src | (subrow2 << 18).
__global__ __launch_bounds__(512) void csr_seg_sort_kernel(
    const int* __restrict__ gbase, const int* __restrict__ gcounts,
    const int2* __restrict__ binned, int2* __restrict__ binned2,
    int2* __restrict__ segptr)
{
    __shared__ int h[256];
    __shared__ int off[256];
    __shared__ int cur[256];
    int b = blockIdx.x;
    int s = gbase[b];
    int n = gcounts[b];
    int t = threadIdx.x;
    if (t < 256) h[t] = 0;
    __syncthreads();
    for (int k = t; k < n; k += 512) {
        unsigned w = (unsigned)binned[s + k].x;
        int rl = (int)((w >> 18) & 63u);
        int src = (int)(w & 0x3FFFFu);
        int key = ((rl >> 2) << 4) | (src >> 14);   // seg*16 + tile (tile <= 9)
        atomicAdd(&h[key], 1);
    }
    __syncthreads();
    if (t < 256) off[t] = h[t];
    __syncthreads();
    for (int d = 1; d < 256; d <<= 1) {
        int v = 0;
        if (t < 256 && t >= d) v = off[t - d];
        __syncthreads();
        if (t < 256) off[t] += v;     // inclusive scan
        __syncthreads();
    }
    if (t < 256) cur[t] = off[t] - h[t];   // exclusive
    __syncthreads();
    if (t < 16) {
        int start = s + ((t == 0) ? 0 : off[t * 16 - 1]);
        int end   = s + off[t * 16 + 15];
        segptr[b * 16 + t] = make_int2(start, end);
    }
    for (int k = t; k < n; k += 512) {
        int2 m = binned[s + k];
        unsigned w = (unsigned)m.x;
        int rl = (int)((w >> 18) & 63u);
        int src = (int)(w & 0x3FFFFu);
        int key = ((rl >> 2) << 4) | (src >> 14);
        int pos = atomicAdd(&cur[key], 1);
        binned2[s + pos] = make_int2(src | ((rl & 3) << 18), m.y);
    }
}

// ---------------- segmented pull: block/bucket, group/4-rows, b128 LDS accum ----------------
// Block = 256 thr = 4 waves; wave = 4 groups x 16 lanes. Group (wid,grp) owns
// rows [b*64 + wid*16 + grp*4, +4) in a PRIVATE 1KB LDS slice (4 rows x 64
// dims f32); lane covers 4 dims -> ds_read_b128/ds_write_b128 RMW. One wave
// instruction advances 4 edges (one per group). Edges arrive src-tile-ordered
// so co-resident blocks sweep src space together (L2 window). No atomics, no
// barriers.
template <int WRITE_BF16>
__global__ __launch_bounds__(256) void pull_seg_kernel(
    const int2* __restrict__ segptr,
    const int2* __restrict__ cc,
    const unsigned short* __restrict__ xb_prev,  // bf16 gather table (prev layer)
    const unsigned short* __restrict__ xb0,      // bf16 layer-0 table (alpha residual)
    float* __restrict__ outL,                    // f32 combined output layer
    unsigned short* __restrict__ xb_next)        // bf16 table for next layer
{
    __shared__ float y[4 * 1024];   // 16 KB: 4 waves x 4 groups x 4 rows x 64 dims
    int b = blockIdx.x;
    int wid = threadIdx.x >> 6;
    int lane = threadIdx.x & 63;
    int grp = lane >> 4;      // group within wave: 0..3
    int l16 = lane & 15;      // 4-dim slot within row

    float* yw = &y[wid * 1024];
    float4* yz = (float4*)yw;
#pragma unroll
    for (int j = 0; j < 4; ++j) yz[j * 64 + lane] = make_float4(0.f, 0.f, 0.f, 0.f);
    // wave-private slices: no __syncthreads needed

    int2 seg = segptr[b * 16 + wid * 4 + grp];
    int e = seg.x, end = seg.y;
    float* pl = yw + grp * 256 + l16 * 4;   // this group's slice, this lane's dims

    for (; e + 2 <= end; e += 2) {
        int2 m0 = cc[e];
        int2 m1 = cc[e + 1];
        uint2 x0 = *(const uint2*)(xb_prev + (size_t)(m0.x & 0x3FFFF) * DIM + l16 * 4);
        uint2 x1 = *(const uint2*)(xb_prev + (size_t)(m1.x & 0x3FFFF) * DIM + l16 * 4);
        {
            float v = __int_as_float(m0.y);
            float* p = pl + (((unsigned)m0.x >> 18) & 3u) * 64;
            float4 t = *(float4*)p;
            t.x = fmaf(v, __uint_as_float(x0.x << 16), t.x);
            t.y = fmaf(v, __uint_as_float(x0.x & 0xFFFF0000u), t.y);
            t.z = fmaf(v, __uint_as_float(x0.y << 16), t.z);
            t.w = fmaf(v, __uint_as_float(x0.y & 0xFFFF0000u), t.w);
            *(float4*)p = t;
        }
        {
            float v = __int_as_float(m1.y);
            float* p = pl + (((unsigned)m1.x >> 18) & 3u) * 64;
            float4 t = *(float4*)p;
            t.x = fmaf(v, __uint_as_float(x1.x << 16), t.x);
            t.y = fmaf(v, __uint_as_float(x1.x & 0xFFFF0000u), t.y);
            t.z = fmaf(v, __uint_as_float(x1.y << 16), t.z);
            t.w = fmaf(v, __uint_as_float(x1.y & 0xFFFF0000u), t.w);
            *(float4*)p = t;
        }
    }
    if (e < end) {
        int2 m0 = cc[e];
        uint2 x0 = *(const uint2*)(xb_prev + (size_t)(m0.x & 0x3FFFF) * DIM + l16 * 4);
        float v = __int_as_float(m0.y);
        float* p = pl + (((unsigned)m0.x >> 18) & 3u) * 64;
        float4 t = *(float4*)p;
        t.x = fmaf(v, __uint_as_float(x0.x << 16), t.x);
        t.y = fmaf(v, __uint_as_float(x0.x & 0xFFFF0000u), t.y);
        t.z = fmaf(v, __uint_as_float(x0.y << 16), t.z);
        t.w = fmaf(v, __uint_as_float(x0.y & 0xFFFF0000u), t.w);
        *(float4*)p = t;
    }

    // epilogue: wave reads its own 16 rows (lane = dim), + alpha*e0, NT store
    int row0 = b * BROWS + wid * 16;
#pragma unroll
    for (int g2 = 0; g2 < 4; ++g2) {
#pragma unroll
        for (int sr = 0; sr < 4; ++sr) {
            int row = row0 + g2 * 4 + sr;
            if (row >= TROWS) continue;
            float acc = yw[g2 * 256 + sr * 64 + lane];
            float e0 = bf2f(xb0[(size_t)row * DIM + lane]);
            float o = fmaf(ALPHA, e0, acc);
            __builtin_nontemporal_store(o, &outL[(size_t)row * DIM + lane]);
            if (WRITE_BF16) xb_next[(size_t)row * DIM + lane] = f2bf(o);
        }
    }
}

// ---------------- fallback (round-1 atomic path) ----------------
__global__ __launch_bounds__(256) void init_out_kernel(const float4* __restrict__ ue,
                                                       const float4* __restrict__ ie,
                                                       float4* __restrict__ out) {
    const int nU4 = NUSERS * DIM / 4;
    const int nT4 = TROWS * DIM / 4;
    int i = blockIdx.x * 256 + threadIdx.x;
    if (i >= nT4) return;
    float4 v = (i < nU4) ? ue[i] : ie[i - nU4];
    out[i] = v;
    float4 a = make_float4(ALPHA * v.x, ALPHA * v.y, ALPHA * v.z, ALPHA * v.w);
    out[nT4 + i] = a;
    out[2 * nT4 + i] = a;
}

__global__ __launch_bounds__(256) void spmm_layer_kernel(
    const int* __restrict__ ui_rows, const int* __restrict__ ui_cols,
    const float* __restrict__ ui_vals,
    const int* __restrict__ iu_rows, const int* __restrict__ iu_cols,
    const float* __restrict__ iu_vals,
    const float* __restrict__ x_items, const float* __restrict__ x_users,
    float* __restrict__ y_users, float* __restrict__ y_items)
{
    unsigned tid = blockIdx.x * 256u + threadIdx.x;
    unsigned d = tid & 63u;
    unsigned e = tid >> 6;
    if (e < NNZ) {
        int r = ui_rows[e];
        int c = ui_cols[e];
        float v = ui_vals[e];
        atomicAdd(&y_users[r * DIM + d], v * x_items[c * DIM + d]);
    } else {
        e -= NNZ;
        if (e < NNZ) {
            int r = iu_rows[e];
            int c = iu_cols[e];
            float v = iu_vals[e];
            atomicAdd(&y_items[r * DIM + d], v * x_users[c * DIM + d]);
        }
    }
}

extern "C" void kernel_launch(void* const* d_in, const int* in_sizes, int n_in,
                              void* d_out, int out_size, void* d_ws, size_t ws_size,
                              hipStream_t stream) {
    const float* ue      = (const float*)d_in[0];
    const float* ie      = (const float*)d_in[1];
    const float* ui_vals = (const float*)d_in[2];
    const float* iu_vals = (const float*)d_in[3];
    const int*   ui_rows = (const int*)d_in[4];
    const int*   ui_cols = (const int*)d_in[5];
    const int*   iu_rows = (const int*)d_in[6];
    const int*   iu_cols = (const int*)d_in[7];
    float* out = (float*)d_out;

    float* L1 = out + (size_t)LSTRIDE;
    float* L2 = out + (size_t)2 * LSTRIDE;

    // ws layout: gcounts[2560] gbase[2560] gcursor[2560] | segptr int2[NSEG]
    //            | binned int2[NEDGES] | binned2 int2[NEDGES]
    //            | xb0 ushort[TROWS*64] | xb1 ushort[TROWS*64]
    const size_t NB_PAD = 2560;
    const size_t cnt_bytes    = NB_PAD * 3 * 4;              // 30720
    const size_t seg_bytes    = (size_t)NSEG * 8;            // 300032
    const size_t hdr_bytes    = cnt_bytes + seg_bytes;       // 330752, 8B-aligned
    const size_t binned_bytes = (size_t)NEDGES * 8;          // 25.6 MB
    const size_t xb_bytes     = (size_t)TROWS * DIM * 2;     // 19.2 MB
    const size_t need_bf16 = hdr_bytes + 2 * binned_bytes + 2 * xb_bytes;  // ~90 MB

    if (ws_size < need_bf16) {
        // fallback: atomic scatter path (round-1, known-good)
        const int nT4 = TROWS * DIM / 4;
        init_out_kernel<<<(nT4 + 255) / 256, 256, 0, stream>>>(
            (const float4*)ue, (const float4*)ie, (float4*)out);
        float* u1 = L1; float* i1 = L1 + (size_t)NUSERS * DIM;
        float* u2 = L2; float* i2 = L2 + (size_t)NUSERS * DIM;
        const unsigned nblocks = (2u * NNZ * 64u) / 256u;
        spmm_layer_kernel<<<nblocks, 256, 0, stream>>>(
            ui_rows, ui_cols, ui_vals, iu_rows, iu_cols, iu_vals, ie, ue, u1, i1);
        spmm_layer_kernel<<<nblocks, 256, 0, stream>>>(
            ui_rows, ui_cols, ui_vals, iu_rows, iu_cols, iu_vals, i1, u1, u2, i2);
        return;
    }

    int* gcounts = (int*)d_ws;
    int* gbase   = gcounts + NB_PAD;
    int* gcursor = gbase + NB_PAD;
    int2* segptr  = (int2*)((char*)d_ws + cnt_bytes);
    int2* binned  = (int2*)((char*)d_ws + hdr_bytes);
    int2* binned2 = (int2*)((char*)binned + binned_bytes);
    unsigned short* xb0 = (unsigned short*)((char*)binned2 + binned_bytes);
    unsigned short* xb1 = xb0 + (size_t)TROWS * DIM;

    hipMemsetAsync(gcounts, 0, NB_PAD * sizeof(int), stream);

    const int nT4 = TROWS * DIM / 4;
    init_copy_kernel<1><<<(nT4 + 255) / 256, 256, 0, stream>>>(
        (const float4*)ue, (const float4*)ie, (float4*)out, (ushort4*)xb0);

    bucket_hist_kernel<<<NCHUNK_H, 256, 0, stream>>>(ui_rows, iu_rows, gcounts);
    scan_buckets_kernel<<<1, 64, 0, stream>>>(gcounts, gbase, gcursor);
    bin_scatter_kernel<<<NCHUNK_S, 512, 0, stream>>>(
        ui_rows, ui_cols, ui_vals, iu_rows, iu_cols, iu_vals, gcursor, binned);
    csr_seg_sort_kernel<<<NBUCK, 512, 0, stream>>>(
        gbase, gcounts, binned, binned2, segptr);

    pull_seg_kernel<1><<<NBUCK, 256, 0, stream>>>(
        segptr, binned2, xb0, xb0, L1, xb1);
    pull_seg_kernel<0><<<NBUCK, 256, 0, stream>>>(
        segptr, binned2, xb1, xb0, L2, nullptr);
}

// Round 11
// 309.142 us; speedup vs baseline: 1.1193x; 1.0290x over previous
//
#include <hip/hip_runtime.h>

#define NUSERS 100000
#define NITEMS 50000
#define DIM 64
#define NNZ 1600000
#define ALPHA 0.1f
#define TROWS (NUSERS + NITEMS)   // 150000 combined rows
#define LSTRIDE (TROWS * DIM)
#define NEDGES (2 * NNZ)          // 3.2M combined edges

#define BROWS 64                            // rows per bucket
#define NBUCK ((TROWS + BROWS - 1) / BROWS) // 2344
#define NSEG (NBUCK * 16)                   // 4-row segments: 16 per bucket

#define CH_H 4096                               // edges per hist block
#define NCHUNK_H ((NEDGES + CH_H - 1) / CH_H)   // 782
#define CH_S 8192                               // edges per scatter block
#define NCHUNK_S ((NEDGES + CH_S - 1) / CH_S)   // 391

typedef float vfloat4 __attribute__((ext_vector_type(4)));

__device__ __forceinline__ unsigned short f2bf(float f) {
    unsigned u = __float_as_uint(f);
    unsigned r = (u + 0x7FFFu + ((u >> 16) & 1u)) >> 16;   // RNE
    return (unsigned short)r;
}

__device__ __forceinline__ float bf2f(unsigned short b) {
    return __uint_as_float(((unsigned)b) << 16);
}

// ---------------- layer-0 copy + bf16 table ----------------
template <int MAKE_BF16>
__global__ __launch_bounds__(256) void init_copy_kernel(const float4* __restrict__ ue,
                                                        const float4* __restrict__ ie,
                                                        float4* __restrict__ out,
                                                        ushort4* __restrict__ xb0) {
    const int nU4 = NUSERS * DIM / 4;
    const int nT4 = TROWS * DIM / 4;
    int i = blockIdx.x * 256 + threadIdx.x;
    if (i >= nT4) return;
    float4 v = (i < nU4) ? ue[i] : ie[i - nU4];
    out[i] = v;
    if (MAKE_BF16) {
        ushort4 b;
        b.x = f2bf(v.x); b.y = f2bf(v.y); b.z = f2bf(v.z); b.w = f2bf(v.w);
        xb0[i] = b;
    }
}

// ---------------- bucket histogram (block-privatized, int LDS atomics) ----------------
__global__ __launch_bounds__(256) void bucket_hist_kernel(const int* __restrict__ ui_rows,
                                                          const int* __restrict__ iu_rows,
                                                          int* __restrict__ gcounts) {
    __shared__ int h[NBUCK];
    for (int t = threadIdx.x; t < NBUCK; t += 256) h[t] = 0;
    __syncthreads();
    int base = blockIdx.x * CH_H;
    for (int j = threadIdx.x; j < CH_H; j += 256) {
        int i = base + j;
        if (i >= NEDGES) break;
        int crow = (i < NNZ) ? ui_rows[i] : (NUSERS + iu_rows[i - NNZ]);
        atomicAdd(&h[crow >> 6], 1);
    }
    __syncthreads();
    for (int t = threadIdx.x; t < NBUCK; t += 256) {
        int c = h[t];
        if (c) atomicAdd(&gcounts[t], c);
    }
}

// ---------------- exclusive scan of bucket counts (one wave) ----------------
__global__ void scan_buckets_kernel(const int* __restrict__ gcounts,
                                    int* __restrict__ gbase,
                                    int* __restrict__ gcursor) {
    int lane = threadIdx.x;   // blockDim = 64, single wave
    int carry = 0;
    for (int b0 = 0; b0 < NBUCK; b0 += 64) {
        int idx = b0 + lane;
        int c = (idx < NBUCK) ? gcounts[idx] : 0;
        int x = c;
        for (int off = 1; off < 64; off <<= 1) {
            int u = __shfl_up(x, off, 64);
            if (lane >= off) x += u;
        }
        int excl = carry + x - c;
        if (idx < NBUCK) { gbase[idx] = excl; gcursor[idx] = excl; }
        carry += __shfl(x, 63, 64);
    }
}

// ---------------- binned scatter: contiguous per-(block,bucket) runs ----------------
// payload word0 = src | (row_local << 18)   (src < 2^18, row_local < 64)
__global__ __launch_bounds__(512) void bin_scatter_kernel(
    const int* __restrict__ ui_rows, const int* __restrict__ ui_cols,
    const float* __restrict__ ui_vals,
    const int* __restrict__ iu_rows, const int* __restrict__ iu_cols,
    const float* __restrict__ iu_vals,
    int* __restrict__ gcursor, int2* __restrict__ binned)
{
    __shared__ int h[NBUCK];
    __shared__ int bbase[NBUCK];
    for (int t = threadIdx.x; t < NBUCK; t += 512) h[t] = 0;
    __syncthreads();
    int base = blockIdx.x * CH_S;
    for (int j = threadIdx.x; j < CH_S; j += 512) {
        int i = base + j;
        if (i >= NEDGES) break;
        int crow = (i < NNZ) ? ui_rows[i] : (NUSERS + iu_rows[i - NNZ]);
        atomicAdd(&h[crow >> 6], 1);
    }
    __syncthreads();
    for (int t = threadIdx.x; t < NBUCK; t += 512) {
        int c = h[t];
        bbase[t] = c ? atomicAdd(&gcursor[t], c) : 0;
        h[t] = 0;
    }
    __syncthreads();
    for (int j = threadIdx.x; j < CH_S; j += 512) {
        int i = base + j;
        if (i >= NEDGES) break;
        int crow, src; float val;
        if (i < NNZ) {
            crow = ui_rows[i]; src = NUSERS + ui_cols[i]; val = ui_vals[i];
        } else {
            int k = i - NNZ;
            crow = NUSERS + iu_rows[k]; src = iu_cols[k]; val = iu_vals[k];
        }
        int b = crow >> 6;
        int off = atomicAdd(&h[b], 1);
        binned[bbase[b] + off] = make_int2(src | ((crow & 63) << 18), __float_as_int(val));
    }
}

// ---------------- segment sort: key = (4-row segment, src_tile) ----------------
// Counting sort (256 keys) per 64-row bucket: 16 segments x 16 tile slots.
// Segment seg owns rows [seg*4, seg*4+4); within a segment edges are
// src-tile-ordered (tile = src>>14, 2MB windows). Payload re-packed as
// src | (subrow2 << 18).
__global__ __launch_bounds__(512) void csr_seg_sort_kernel(
    const int* __restrict__ gbase, const int* __restrict__ gcounts,
    const int2* __restrict__ binned, int2* __restrict__ binned2,
    int2* __restrict__ segptr)
{
    __shared__ int h[256];
    __shared__ int off[256];
    __shared__ int cur[256];
    int b = blockIdx.x;
    int s = gbase[b];
    int n = gcounts[b];
    int t = threadIdx.x;
    if (t < 256) h[t] = 0;
    __syncthreads();
    for (int k = t; k < n; k += 512) {
        unsigned w = (unsigned)binned[s + k].x;
        int rl = (int)((w >> 18) & 63u);
        int src = (int)(w & 0x3FFFFu);
        int key = ((rl >> 2) << 4) | (src >> 14);   // seg*16 + tile (tile <= 9)
        atomicAdd(&h[key], 1);
    }
    __syncthreads();
    if (t < 256) off[t] = h[t];
    __syncthreads();
    for (int d = 1; d < 256; d <<= 1) {
        int v = 0;
        if (t < 256 && t >= d) v = off[t - d];
        __syncthreads();
        if (t < 256) off[t] += v;     // inclusive scan
        __syncthreads();
    }
    if (t < 256) cur[t] = off[t] - h[t];   // exclusive
    __syncthreads();
    if (t < 16) {
        int start = s + ((t == 0) ? 0 : off[t * 16 - 1]);
        int end   = s + off[t * 16 + 15];
        segptr[b * 16 + t] = make_int2(start, end);
    }
    for (int k = t; k < n; k += 512) {
        int2 m = binned[s + k];
        unsigned w = (unsigned)m.x;
        int rl = (int)((w >> 18) & 63u);
        int src = (int)(w & 0x3FFFFu);
        int key = ((rl >> 2) << 4) | (src >> 14);
        int pos = atomicAdd(&cur[key], 1);
        binned2[s + pos] = make_int2(src | ((rl & 3) << 18), m.y);
    }
}

// ---------------- segmented pull: block/bucket, group/4-rows, REGISTER accum ----------------
// Block = 256 thr = 4 waves; wave = 4 groups x 16 lanes. Group (wid,grp) owns
// rows [b*64 + (wid*4+grp)*4, +4) in four float4 REGISTER accumulators; the
// subrow (2 bits in payload) selects via predicated FMA (v = cndmask(v,0)).
// No LDS, no atomics -> full occupancy; edges arrive src-tile-ordered so
// co-resident blocks sweep the gather table through L2 together.
#define EDGE_ACC(m, xw)                                                       \
    do {                                                                      \
        unsigned rr = ((unsigned)(m).x >> 18) & 3u;                           \
        float v = __int_as_float((m).y);                                      \
        float xv0 = __uint_as_float((xw).x << 16);                            \
        float xv1 = __uint_as_float((xw).x & 0xFFFF0000u);                    \
        float xv2 = __uint_as_float((xw).y << 16);                            \
        float xv3 = __uint_as_float((xw).y & 0xFFFF0000u);                    \
        float p0 = (rr == 0u) ? v : 0.f;                                      \
        float p1 = (rr == 1u) ? v : 0.f;                                      \
        float p2 = (rr == 2u) ? v : 0.f;                                      \
        float p3 = (rr == 3u) ? v : 0.f;                                      \
        a0.x = fmaf(p0, xv0, a0.x); a0.y = fmaf(p0, xv1, a0.y);               \
        a0.z = fmaf(p0, xv2, a0.z); a0.w = fmaf(p0, xv3, a0.w);               \
        a1.x = fmaf(p1, xv0, a1.x); a1.y = fmaf(p1, xv1, a1.y);               \
        a1.z = fmaf(p1, xv2, a1.z); a1.w = fmaf(p1, xv3, a1.w);               \
        a2.x = fmaf(p2, xv0, a2.x); a2.y = fmaf(p2, xv1, a2.y);               \
        a2.z = fmaf(p2, xv2, a2.z); a2.w = fmaf(p2, xv3, a2.w);               \
        a3.x = fmaf(p3, xv0, a3.x); a3.y = fmaf(p3, xv1, a3.y);               \
        a3.z = fmaf(p3, xv2, a3.z); a3.w = fmaf(p3, xv3, a3.w);               \
    } while (0)

#define ROW_OUT(ar, r)                                                        \
    do {                                                                      \
        int row = row0 + (r);                                                 \
        if (row < TROWS) {                                                    \
            uint2 eb = *(const uint2*)(xb0 + (size_t)row * DIM + l16 * 4);    \
            vfloat4 o;                                                        \
            o.x = fmaf(ALPHA, __uint_as_float(eb.x << 16), (ar).x);           \
            o.y = fmaf(ALPHA, __uint_as_float(eb.x & 0xFFFF0000u), (ar).y);   \
            o.z = fmaf(ALPHA, __uint_as_float(eb.y << 16), (ar).z);           \
            o.w = fmaf(ALPHA, __uint_as_float(eb.y & 0xFFFF0000u), (ar).w);   \
            __builtin_nontemporal_store(                                      \
                o, (vfloat4*)(outL + (size_t)row * DIM + l16 * 4));           \
            if (WRITE_BF16) {                                                 \
                ushort4 bb;                                                   \
                bb.x = f2bf(o.x); bb.y = f2bf(o.y);                           \
                bb.z = f2bf(o.z); bb.w = f2bf(o.w);                           \
                *(ushort4*)(xb_next + (size_t)row * DIM + l16 * 4) = bb;      \
            }                                                                 \
        }                                                                     \
    } while (0)

template <int WRITE_BF16>
__global__ __launch_bounds__(256) void pull_seg_kernel(
    const int2* __restrict__ segptr,
    const int2* __restrict__ cc,
    const unsigned short* __restrict__ xb_prev,  // bf16 gather table (prev layer)
    const unsigned short* __restrict__ xb0,      // bf16 layer-0 table (alpha residual)
    float* __restrict__ outL,                    // f32 combined output layer
    unsigned short* __restrict__ xb_next)        // bf16 table for next layer
{
    int b = blockIdx.x;
    int wid = threadIdx.x >> 6;
    int lane = threadIdx.x & 63;
    int grp = lane >> 4;      // group within wave: 0..3
    int l16 = lane & 15;      // 4-dim slot within row
    int seg = wid * 4 + grp;  // 4-row segment: 0..15

    float4 a0 = make_float4(0.f, 0.f, 0.f, 0.f);
    float4 a1 = a0, a2 = a0, a3 = a0;

    int2 sp = segptr[b * 16 + seg];
    int e = sp.x, end = sp.y;
    const unsigned short* xp = xb_prev + l16 * 4;

    // 2-deep: 8 independent gathers in flight per wave
    for (; e + 2 <= end; e += 2) {
        int2 m0 = cc[e];
        int2 m1 = cc[e + 1];
        uint2 x0 = *(const uint2*)(xp + (size_t)(m0.x & 0x3FFFF) * DIM);
        uint2 x1 = *(const uint2*)(xp + (size_t)(m1.x & 0x3FFFF) * DIM);
        EDGE_ACC(m0, x0);
        EDGE_ACC(m1, x1);
    }
    if (e < end) {
        int2 m0 = cc[e];
        uint2 x0 = *(const uint2*)(xp + (size_t)(m0.x & 0x3FFFF) * DIM);
        EDGE_ACC(m0, x0);
    }

    // epilogue: + alpha*e0 (bf16 table), NT store f32, optional bf16 table
    int row0 = b * BROWS + seg * 4;
    ROW_OUT(a0, 0);
    ROW_OUT(a1, 1);
    ROW_OUT(a2, 2);
    ROW_OUT(a3, 3);
}

// ---------------- fallback (round-1 atomic path) ----------------
__global__ __launch_bounds__(256) void init_out_kernel(const float4* __restrict__ ue,
                                                       const float4* __restrict__ ie,
                                                       float4* __restrict__ out) {
    const int nU4 = NUSERS * DIM / 4;
    const int nT4 = TROWS * DIM / 4;
    int i = blockIdx.x * 256 + threadIdx.x;
    if (i >= nT4) return;
    float4 v = (i < nU4) ? ue[i] : ie[i - nU4];
    out[i] = v;
    float4 a = make_float4(ALPHA * v.x, ALPHA * v.y, ALPHA * v.z, ALPHA * v.w);
    out[nT4 + i] = a;
    out[2 * nT4 + i] = a;
}

__global__ __launch_bounds__(256) void spmm_layer_kernel(
    const int* __restrict__ ui_rows, const int* __restrict__ ui_cols,
    const float* __restrict__ ui_vals,
    const int* __restrict__ iu_rows, const int* __restrict__ iu_cols,
    const float* __restrict__ iu_vals,
    const float* __restrict__ x_items, const float* __restrict__ x_users,
    float* __restrict__ y_users, float* __restrict__ y_items)
{
    unsigned tid = blockIdx.x * 256u + threadIdx.x;
    unsigned d = tid & 63u;
    unsigned e = tid >> 6;
    if (e < NNZ) {
        int r = ui_rows[e];
        int c = ui_cols[e];
        float v = ui_vals[e];
        atomicAdd(&y_users[r * DIM + d], v * x_items[c * DIM + d]);
    } else {
        e -= NNZ;
        if (e < NNZ) {
            int r = iu_rows[e];
            int c = iu_cols[e];
            float v = iu_vals[e];
            atomicAdd(&y_items[r * DIM + d], v * x_users[c * DIM + d]);
        }
    }
}

extern "C" void kernel_launch(void* const* d_in, const int* in_sizes, int n_in,
                              void* d_out, int out_size, void* d_ws, size_t ws_size,
                              hipStream_t stream) {
    const float* ue      = (const float*)d_in[0];
    const float* ie      = (const float*)d_in[1];
    const float* ui_vals = (const float*)d_in[2];
    const float* iu_vals = (const float*)d_in[3];
    const int*   ui_rows = (const int*)d_in[4];
    const int*   ui_cols = (const int*)d_in[5];
    const int*   iu_rows = (const int*)d_in[6];
    const int*   iu_cols = (const int*)d_in[7];
    float* out = (float*)d_out;

    float* L1 = out + (size_t)LSTRIDE;
    float* L2 = out + (size_t)2 * LSTRIDE;

    // ws layout: gcounts[2560] gbase[2560] gcursor[2560] | segptr int2[NSEG]
    //            | binned int2[NEDGES] | binned2 int2[NEDGES]
    //            | xb0 ushort[TROWS*64] | xb1 ushort[TROWS*64]
    const size_t NB_PAD = 2560;
    const size_t cnt_bytes    = NB_PAD * 3 * 4;              // 30720
    const size_t seg_bytes    = (size_t)NSEG * 8;            // 300032
    const size_t hdr_bytes    = cnt_bytes + seg_bytes;       // 330752, 8B-aligned
    const size_t binned_bytes = (size_t)NEDGES * 8;          // 25.6 MB
    const size_t xb_bytes     = (size_t)TROWS * DIM * 2;     // 19.2 MB
    const size_t need_bf16 = hdr_bytes + 2 * binned_bytes + 2 * xb_bytes;  // ~90 MB

    if (ws_size < need_bf16) {
        // fallback: atomic scatter path (round-1, known-good)
        const int nT4 = TROWS * DIM / 4;
        init_out_kernel<<<(nT4 + 255) / 256, 256, 0, stream>>>(
            (const float4*)ue, (const float4*)ie, (float4*)out);
        float* u1 = L1; float* i1 = L1 + (size_t)NUSERS * DIM;
        float* u2 = L2; float* i2 = L2 + (size_t)NUSERS * DIM;
        const unsigned nblocks = (2u * NNZ * 64u) / 256u;
        spmm_layer_kernel<<<nblocks, 256, 0, stream>>>(
            ui_rows, ui_cols, ui_vals, iu_rows, iu_cols, iu_vals, ie, ue, u1, i1);
        spmm_layer_kernel<<<nblocks, 256, 0, stream>>>(
            ui_rows, ui_cols, ui_vals, iu_rows, iu_cols, iu_vals, i1, u1, u2, i2);
        return;
    }

    int* gcounts = (int*)d_ws;
    int* gbase   = gcounts + NB_PAD;
    int* gcursor = gbase + NB_PAD;
    int2* segptr  = (int2*)((char*)d_ws + cnt_bytes);
    int2* binned  = (int2*)((char*)d_ws + hdr_bytes);
    int2* binned2 = (int2*)((char*)binned + binned_bytes);
    unsigned short* xb0 = (unsigned short*)((char*)binned2 + binned_bytes);
    unsigned short* xb1 = xb0 + (size_t)TROWS * DIM;

    hipMemsetAsync(gcounts, 0, NB_PAD * sizeof(int), stream);

    const int nT4 = TROWS * DIM / 4;
    init_copy_kernel<1><<<(nT4 + 255) / 256, 256, 0, stream>>>(
        (const float4*)ue, (const float4*)ie, (float4*)out, (ushort4*)xb0);

    bucket_hist_kernel<<<NCHUNK_H, 256, 0, stream>>>(ui_rows, iu_rows, gcounts);
    scan_buckets_kernel<<<1, 64, 0, stream>>>(gcounts, gbase, gcursor);
    bin_scatter_kernel<<<NCHUNK_S, 512, 0, stream>>>(
        ui_rows, ui_cols, ui_vals, iu_rows, iu_cols, iu_vals, gcursor, binned);
    csr_seg_sort_kernel<<<NBUCK, 512, 0, stream>>>(
        gbase, gcounts, binned, binned2, segptr);

    pull_seg_kernel<1><<<NBUCK, 256, 0, stream>>>(
        segptr, binned2, xb0, xb0, L1, xb1);
    pull_seg_kernel<0><<<NBUCK, 256, 0, stream>>>(
        segptr, binned2, xb1, xb0, L2, nullptr);
}

// Round 12
// 295.762 us; speedup vs baseline: 1.1700x; 1.0452x over previous
//
#include <hip/hip_runtime.h>

#define NUSERS 100000
#define NITEMS 50000
#define DIM 64
#define NNZ 1600000
#define ALPHA 0.1f
#define TROWS (NUSERS + NITEMS)   // 150000 combined rows
#define LSTRIDE (TROWS * DIM)
#define NEDGES (2 * NNZ)          // 3.2M combined edges

#define BROWS 64                            // rows per sort bucket
#define NBUCK ((TROWS + BROWS - 1) / BROWS) // 2344
#define NKEY 640                            // 64 rows x 10 src tiles

#define CH_H 4096                               // edges per hist block
#define NCHUNK_H ((NEDGES + CH_H - 1) / CH_H)   // 782
#define CH_S 8192                               // edges per scatter block
#define NCHUNK_S ((NEDGES + CH_S - 1) / CH_S)   // 391

#define PROWS 16                            // rows per pull block
#define NPBLK (TROWS / PROWS)               // 9375 (exact)

typedef float vfloat4 __attribute__((ext_vector_type(4)));

__device__ __forceinline__ unsigned short f2bf(float f) {
    unsigned u = __float_as_uint(f);
    unsigned r = (u + 0x7FFFu + ((u >> 16) & 1u)) >> 16;   // RNE
    return (unsigned short)r;
}

__device__ __forceinline__ float bf_lo(unsigned u) { return __uint_as_float(u << 16); }
__device__ __forceinline__ float bf_hi(unsigned u) { return __uint_as_float(u & 0xFFFF0000u); }

// ---------------- layer-0 copy + bf16 table ----------------
__global__ __launch_bounds__(256) void init_copy_kernel(const float4* __restrict__ ue,
                                                        const float4* __restrict__ ie,
                                                        float4* __restrict__ out,
                                                        ushort4* __restrict__ xb0) {
    const int nU4 = NUSERS * DIM / 4;
    const int nT4 = TROWS * DIM / 4;
    int i = blockIdx.x * 256 + threadIdx.x;
    if (i >= nT4) return;
    float4 v = (i < nU4) ? ue[i] : ie[i - nU4];
    out[i] = v;
    ushort4 b;
    b.x = f2bf(v.x); b.y = f2bf(v.y); b.z = f2bf(v.z); b.w = f2bf(v.w);
    xb0[i] = b;
}

// ---------------- bucket histogram (block-privatized, int LDS atomics) ----------------
__global__ __launch_bounds__(256) void bucket_hist_kernel(const int* __restrict__ ui_rows,
                                                          const int* __restrict__ iu_rows,
                                                          int* __restrict__ gcounts) {
    __shared__ int h[NBUCK];
    for (int t = threadIdx.x; t < NBUCK; t += 256) h[t] = 0;
    __syncthreads();
    int base = blockIdx.x * CH_H;
    for (int j = threadIdx.x; j < CH_H; j += 256) {
        int i = base + j;
        if (i >= NEDGES) break;
        int crow = (i < NNZ) ? ui_rows[i] : (NUSERS + iu_rows[i - NNZ]);
        atomicAdd(&h[crow >> 6], 1);
    }
    __syncthreads();
    for (int t = threadIdx.x; t < NBUCK; t += 256) {
        int c = h[t];
        if (c) atomicAdd(&gcounts[t], c);
    }
}

// ---------------- exclusive scan of bucket counts (one wave) ----------------
__global__ void scan_buckets_kernel(const int* __restrict__ gcounts,
                                    int* __restrict__ gbase,
                                    int* __restrict__ gcursor) {
    int lane = threadIdx.x;   // blockDim = 64, single wave
    int carry = 0;
    for (int b0 = 0; b0 < NBUCK; b0 += 64) {
        int idx = b0 + lane;
        int c = (idx < NBUCK) ? gcounts[idx] : 0;
        int x = c;
        for (int off = 1; off < 64; off <<= 1) {
            int u = __shfl_up(x, off, 64);
            if (lane >= off) x += u;
        }
        int excl = carry + x - c;
        if (idx < NBUCK) { gbase[idx] = excl; gcursor[idx] = excl; }
        carry += __shfl(x, 63, 64);
    }
}

// ---------------- binned scatter: contiguous per-(block,bucket) runs ----------------
// payload word0 = src | (row_local << 18)   (src < 2^18, row_local < 64)
__global__ __launch_bounds__(512) void bin_scatter_kernel(
    const int* __restrict__ ui_rows, const int* __restrict__ ui_cols,
    const float* __restrict__ ui_vals,
    const int* __restrict__ iu_rows, const int* __restrict__ iu_cols,
    const float* __restrict__ iu_vals,
    int* __restrict__ gcursor, int2* __restrict__ binned)
{
    __shared__ int h[NBUCK];
    __shared__ int bbase[NBUCK];
    for (int t = threadIdx.x; t < NBUCK; t += 512) h[t] = 0;
    __syncthreads();
    int base = blockIdx.x * CH_S;
    for (int j = threadIdx.x; j < CH_S; j += 512) {
        int i = base + j;
        if (i >= NEDGES) break;
        int crow = (i < NNZ) ? ui_rows[i] : (NUSERS + iu_rows[i - NNZ]);
        atomicAdd(&h[crow >> 6], 1);
    }
    __syncthreads();
    for (int t = threadIdx.x; t < NBUCK; t += 512) {
        int c = h[t];
        bbase[t] = c ? atomicAdd(&gcursor[t], c) : 0;
        h[t] = 0;
    }
    __syncthreads();
    for (int j = threadIdx.x; j < CH_S; j += 512) {
        int i = base + j;
        if (i >= NEDGES) break;
        int crow, src; float val;
        if (i < NNZ) {
            crow = ui_rows[i]; src = NUSERS + ui_cols[i]; val = ui_vals[i];
        } else {
            int k = i - NNZ;
            crow = NUSERS + iu_rows[k]; src = iu_cols[k]; val = iu_vals[k];
        }
        int b = crow >> 6;
        int off = atomicAdd(&h[b], 1);
        binned[bbase[b] + off] = make_int2(src | ((crow & 63) << 18), __float_as_int(val));
    }
}

// ---------------- row+tile sort: key = row_local*10 + src_tile ----------------
// Counting sort (640 keys) per 64-row bucket. Rows become contiguous
// (global rowptr emitted); within a row edges are src-tile-ordered
// (tile = src>>14, 2MB windows). Output payload = plain (src, val).
__global__ __launch_bounds__(512) void csr_sort_kernel(
    const int* __restrict__ gbase, const int* __restrict__ gcounts,
    const int2* __restrict__ binned, int2* __restrict__ binned2,
    int* __restrict__ rowptr)
{
    __shared__ int h[NKEY];
    __shared__ int off[NKEY];   // global inclusive prefix
    __shared__ int cur[NKEY];
    int b = blockIdx.x;
    int s = gbase[b];
    int n = gcounts[b];
    int t = threadIdx.x;
    for (int k = t; k < NKEY; k += 512) h[k] = 0;
    __syncthreads();
    for (int k = t; k < n; k += 512) {
        unsigned w = (unsigned)binned[s + k].x;
        int rl = (int)((w >> 18) & 63u);
        int src = (int)(w & 0x3FFFFu);
        atomicAdd(&h[rl * 10 + (src >> 14)], 1);
    }
    __syncthreads();
    // hierarchical scan on one wave: lane = row_local, 10 serial + wave scan
    if (t < 64) {
        int base = t * 10;
        int vals[10];
        int run = 0;
#pragma unroll
        for (int j = 0; j < 10; ++j) { run += h[base + j]; vals[j] = run; }
        int x = run;
        for (int o = 1; o < 64; o <<= 1) {
            int u = __shfl_up(x, o, 64);
            if (t >= o) x += u;
        }
        int excl = x - run;   // edges in rows < t of this bucket
#pragma unroll
        for (int j = 0; j < 10; ++j) off[base + j] = excl + vals[j];
        rowptr[b * BROWS + t] = s + excl;   // padded array; rows >= TROWS harmless
    }
    __syncthreads();
    for (int k = t; k < NKEY; k += 512) cur[k] = off[k] - h[k];
    __syncthreads();
    for (int k = t; k < n; k += 512) {
        int2 m = binned[s + k];
        unsigned w = (unsigned)m.x;
        int rl = (int)((w >> 18) & 63u);
        int src = (int)(w & 0x3FFFFu);
        int pos = atomicAdd(&cur[rl * 10 + (src >> 14)], 1);
        binned2[s + pos] = make_int2(src, m.y);
    }
}

// ---------------- row pull: group-per-row, plain register accum ----------------
// Block = 256 thr = 16 groups of 16 lanes; group owns one row (4 dims/lane,
// float4 acc). No LDS, no predication, no reduce. Edges of each row are
// src-tile-ordered so co-resident blocks sweep the gather table through L2.
template <int WRITE_BF16>
__global__ __launch_bounds__(256) void pull_row_kernel(
    const int* __restrict__ rowptr, const int2* __restrict__ cc,
    const unsigned short* __restrict__ xb_prev,  // bf16 gather table (prev layer)
    const unsigned short* __restrict__ xb0,      // bf16 layer-0 table (alpha residual)
    float* __restrict__ outL,                    // f32 combined output layer
    unsigned short* __restrict__ xb_next)        // bf16 table for next layer
{
    int grp16 = threadIdx.x >> 4;          // group 0..15
    int l16 = threadIdx.x & 15;            // 4-dim slot within row
    int row = blockIdx.x * PROWS + grp16;  // grid covers TROWS exactly

    float4 acc = make_float4(0.f, 0.f, 0.f, 0.f);
    int e = rowptr[row];
    int end = rowptr[row + 1];
    const unsigned short* xp = xb_prev + l16 * 4;

    for (; e + 2 <= end; e += 2) {
        int2 m0 = cc[e];
        int2 m1 = cc[e + 1];
        uint2 x0 = *(const uint2*)(xp + (size_t)m0.x * DIM);
        uint2 x1 = *(const uint2*)(xp + (size_t)m1.x * DIM);
        float v0 = __int_as_float(m0.y);
        float v1 = __int_as_float(m1.y);
        acc.x = fmaf(v0, bf_lo(x0.x), acc.x);
        acc.y = fmaf(v0, bf_hi(x0.x), acc.y);
        acc.z = fmaf(v0, bf_lo(x0.y), acc.z);
        acc.w = fmaf(v0, bf_hi(x0.y), acc.w);
        acc.x = fmaf(v1, bf_lo(x1.x), acc.x);
        acc.y = fmaf(v1, bf_hi(x1.x), acc.y);
        acc.z = fmaf(v1, bf_lo(x1.y), acc.z);
        acc.w = fmaf(v1, bf_hi(x1.y), acc.w);
    }
    if (e < end) {
        int2 m0 = cc[e];
        uint2 x0 = *(const uint2*)(xp + (size_t)m0.x * DIM);
        float v0 = __int_as_float(m0.y);
        acc.x = fmaf(v0, bf_lo(x0.x), acc.x);
        acc.y = fmaf(v0, bf_hi(x0.x), acc.y);
        acc.z = fmaf(v0, bf_lo(x0.y), acc.z);
        acc.w = fmaf(v0, bf_hi(x0.y), acc.w);
    }

    // epilogue: + alpha*e0 (bf16 table), NT store f32, optional bf16 table
    size_t obase = (size_t)row * DIM + l16 * 4;
    uint2 eb = *(const uint2*)(xb0 + obase);
    vfloat4 o;
    o.x = fmaf(ALPHA, bf_lo(eb.x), acc.x);
    o.y = fmaf(ALPHA, bf_hi(eb.x), acc.y);
    o.z = fmaf(ALPHA, bf_lo(eb.y), acc.z);
    o.w = fmaf(ALPHA, bf_hi(eb.y), acc.w);
    __builtin_nontemporal_store(o, (vfloat4*)(outL + obase));
    if (WRITE_BF16) {
        ushort4 bb;
        bb.x = f2bf(o.x); bb.y = f2bf(o.y); bb.z = f2bf(o.z); bb.w = f2bf(o.w);
        *(ushort4*)(xb_next + obase) = bb;
    }
}

// ---------------- fallback (round-1 atomic path) ----------------
__global__ __launch_bounds__(256) void init_out_kernel(const float4* __restrict__ ue,
                                                       const float4* __restrict__ ie,
                                                       float4* __restrict__ out) {
    const int nU4 = NUSERS * DIM / 4;
    const int nT4 = TROWS * DIM / 4;
    int i = blockIdx.x * 256 + threadIdx.x;
    if (i >= nT4) return;
    float4 v = (i < nU4) ? ue[i] : ie[i - nU4];
    out[i] = v;
    float4 a = make_float4(ALPHA * v.x, ALPHA * v.y, ALPHA * v.z, ALPHA * v.w);
    out[nT4 + i] = a;
    out[2 * nT4 + i] = a;
}

__global__ __launch_bounds__(256) void spmm_layer_kernel(
    const int* __restrict__ ui_rows, const int* __restrict__ ui_cols,
    const float* __restrict__ ui_vals,
    const int* __restrict__ iu_rows, const int* __restrict__ iu_cols,
    const float* __restrict__ iu_vals,
    const float* __restrict__ x_items, const float* __restrict__ x_users,
    float* __restrict__ y_users, float* __restrict__ y_items)
{
    unsigned tid = blockIdx.x * 256u + threadIdx.x;
    unsigned d = tid & 63u;
    unsigned e = tid >> 6;
    if (e < NNZ) {
        int r = ui_rows[e];
        int c = ui_cols[e];
        float v = ui_vals[e];
        atomicAdd(&y_users[r * DIM + d], v * x_items[c * DIM + d]);
    } else {
        e -= NNZ;
        if (e < NNZ) {
            int r = iu_rows[e];
            int c = iu_cols[e];
            float v = iu_vals[e];
            atomicAdd(&y_items[r * DIM + d], v * x_users[c * DIM + d]);
        }
    }
}

extern "C" void kernel_launch(void* const* d_in, const int* in_sizes, int n_in,
                              void* d_out, int out_size, void* d_ws, size_t ws_size,
                              hipStream_t stream) {
    const float* ue      = (const float*)d_in[0];
    const float* ie      = (const float*)d_in[1];
    const float* ui_vals = (const float*)d_in[2];
    const float* iu_vals = (const float*)d_in[3];
    const int*   ui_rows = (const int*)d_in[4];
    const int*   ui_cols = (const int*)d_in[5];
    const int*   iu_rows = (const int*)d_in[6];
    const int*   iu_cols = (const int*)d_in[7];
    float* out = (float*)d_out;

    float* L1 = out + (size_t)LSTRIDE;
    float* L2 = out + (size_t)2 * LSTRIDE;

    // ws layout: gcounts[2560] gbase[2560] gcursor[2560] rowptr[150032]
    //            | binned int2[NEDGES] | binned2 int2[NEDGES]
    //            | xb0 ushort[TROWS*64] | xb1 ushort[TROWS*64]
    const size_t NB_PAD = 2560;
    const size_t RP_PAD = 150032;   // >= NBUCK*BROWS + 1 = 150017
    const size_t hdr_bytes    = (NB_PAD * 3 + RP_PAD) * 4;   // 630848, 8B-aligned
    const size_t binned_bytes = (size_t)NEDGES * 8;          // 25.6 MB
    const size_t xb_bytes     = (size_t)TROWS * DIM * 2;     // 19.2 MB
    const size_t need_bf16 = hdr_bytes + 2 * binned_bytes + 2 * xb_bytes;  // ~90.6 MB

    if (ws_size < need_bf16) {
        // fallback: atomic scatter path (round-1, known-good)
        const int nT4 = TROWS * DIM / 4;
        init_out_kernel<<<(nT4 + 255) / 256, 256, 0, stream>>>(
            (const float4*)ue, (const float4*)ie, (float4*)out);
        float* u1 = L1; float* i1 = L1 + (size_t)NUSERS * DIM;
        float* u2 = L2; float* i2 = L2 + (size_t)NUSERS * DIM;
        const unsigned nblocks = (2u * NNZ * 64u) / 256u;
        spmm_layer_kernel<<<nblocks, 256, 0, stream>>>(
            ui_rows, ui_cols, ui_vals, iu_rows, iu_cols, iu_vals, ie, ue, u1, i1);
        spmm_layer_kernel<<<nblocks, 256, 0, stream>>>(
            ui_rows, ui_cols, ui_vals, iu_rows, iu_cols, iu_vals, i1, u1, u2, i2);
        return;
    }

    int* gcounts = (int*)d_ws;
    int* gbase   = gcounts + NB_PAD;
    int* gcursor = gbase + NB_PAD;
    int* rowptr  = gcursor + NB_PAD;
    int2* binned  = (int2*)((char*)d_ws + hdr_bytes);
    int2* binned2 = (int2*)((char*)binned + binned_bytes);
    unsigned short* xb0 = (unsigned short*)((char*)binned2 + binned_bytes);
    unsigned short* xb1 = xb0 + (size_t)TROWS * DIM;

    hipMemsetAsync(gcounts, 0, NB_PAD * sizeof(int), stream);

    const int nT4 = TROWS * DIM / 4;
    init_copy_kernel<<<(nT4 + 255) / 256, 256, 0, stream>>>(
        (const float4*)ue, (const float4*)ie, (float4*)out, (ushort4*)xb0);

    bucket_hist_kernel<<<NCHUNK_H, 256, 0, stream>>>(ui_rows, iu_rows, gcounts);
    scan_buckets_kernel<<<1, 64, 0, stream>>>(gcounts, gbase, gcursor);
    bin_scatter_kernel<<<NCHUNK_S, 512, 0, stream>>>(
        ui_rows, ui_cols, ui_vals, iu_rows, iu_cols, iu_vals, gcursor, binned);
    csr_sort_kernel<<<NBUCK, 512, 0, stream>>>(
        gbase, gcounts, binned, binned2, rowptr);

    pull_row_kernel<1><<<NPBLK, 256, 0, stream>>>(
        rowptr, binned2, xb0, xb0, L1, xb1);
    pull_row_kernel<0><<<NPBLK, 256, 0, stream>>>(
        rowptr, binned2, xb1, xb0, L2, nullptr);
}